// Round 21
// baseline (266.475 us; speedup 1.0000x reference)
//
#include <hip/hip_runtime.h>
#include <math.h>

typedef __attribute__((ext_vector_type(4))) float f32x4;
typedef __attribute__((ext_vector_type(8))) short bf16x8;

typedef __attribute__((address_space(3))) void lds_void;
typedef const __attribute__((address_space(1))) void gbl_void;

__device__ __forceinline__ unsigned short f2bf(float f) {
  unsigned int u = __builtin_bit_cast(unsigned int, f);
  u += 0x7FFFu + ((u >> 16) & 1u);
  return (unsigned short)(u >> 16);
}

__device__ __forceinline__ float bf2f(unsigned short u) {
  return __builtin_bit_cast(float, (unsigned int)u << 16);
}

__device__ __forceinline__ f32x4 mfma16(bf16x8 a, bf16x8 b, f32x4 c) {
  return __builtin_amdgcn_mfma_f32_16x16x32_bf16(a, b, c, 0, 0, 0);
}

// ---------------- prep: fold BN into W (bf16) + bias (f32) ----------------
__global__ void prep_kernel(const float* __restrict__ W, const float* __restrict__ g,
                            const float* __restrict__ bb, const float* __restrict__ mm,
                            const float* __restrict__ vv,
                            unsigned short* __restrict__ Wout, float* __restrict__ bout,
                            float alpha) {
  int idx = blockIdx.x * 256 + threadIdx.x;
  if (idx < 192 * 192) {
    int o = idx / 192;
    float s = g[o] * rsqrtf(vv[o] + 1e-5f);
    Wout[idx] = f2bf(W[idx] * s * alpha);
  }
  if (idx < 192) {
    float s = g[idx] * rsqrtf(vv[idx] + 1e-5f);
    bout[idx] = (bb[idx] - mm[idx] * s) * alpha;
  }
}

// ---------------- projection: Y = relu(W' X + bias) ----------------
template <int LAYOUT>
__launch_bounds__(256)
__global__ void proj_kernel(const float* __restrict__ X,
                            const unsigned short* __restrict__ Wp,
                            const float* __restrict__ bias,
                            unsigned short* __restrict__ Yv) {
  const int o0 = blockIdx.x * 64;
  const int hw0 = blockIdx.y * 64;
  const int b = blockIdx.z;
  const int w = threadIdx.x >> 6, l = threadIdx.x & 63;
  const int l16 = l & 15, lg = l >> 4;
  const float* Xb = X + (size_t)b * 192 * 4096;

  f32x4 acc[4] = {f32x4{0,0,0,0}, f32x4{0,0,0,0}, f32x4{0,0,0,0}, f32x4{0,0,0,0}};

  for (int ks = 0; ks < 6; ++ks) {
    const int c0 = ks * 32 + lg * 8;
    bf16x8 a = *(const bf16x8*)(Wp + (size_t)(o0 + 16 * w + l16) * 192 + c0);
#pragma unroll
    for (int n = 0; n < 4; ++n) {
      const int hw = hw0 + 16 * n + l16;
      bf16x8 bfr;
#pragma unroll
      for (int j = 0; j < 8; ++j)
        bfr[j] = (short)f2bf(Xb[(size_t)(c0 + j) * 4096 + hw]);
      acc[n] = mfma16(a, bfr, acc[n]);
    }
  }

#pragma unroll
  for (int n = 0; n < 4; ++n) {
    const int hw = hw0 + 16 * n + l16;
    float vv4[4];
#pragma unroll
    for (int r = 0; r < 4; ++r) {
      const int o = o0 + 16 * w + lg * 4 + r;
      vv4[r] = fmaxf(acc[n][r] + bias[o], 0.0f);
    }
    if (LAYOUT == 1) {
      unsigned int lo = (unsigned)f2bf(vv4[0]) | ((unsigned)f2bf(vv4[1]) << 16);
      unsigned int hi = (unsigned)f2bf(vv4[2]) | ((unsigned)f2bf(vv4[3]) << 16);
      uint2 pk; pk.x = lo; pk.y = hi;
      *(uint2*)(Yv + ((size_t)b * 4096 + hw) * 192 + o0 + 16 * w + lg * 4) = pk;
    } else {
#pragma unroll
      for (int r = 0; r < 4; ++r) {
        const int o = o0 + 16 * w + lg * 4 + r;
        Yv[((size_t)b * 192 + o) * 4096 + hw] = f2bf(vv4[r]);
      }
    }
  }
}

// ---------------- final projection with NS-way partial-sum input (f32 out) ----------------
template <int NS>
__launch_bounds__(256)
__global__ void proj_sum_kernel(const float* __restrict__ X,
                                const unsigned short* __restrict__ Wp,
                                const float* __restrict__ bias,
                                float* __restrict__ Yv) {
  const int o0 = blockIdx.x * 64;
  const int hw0 = blockIdx.y * 64;
  const int b = blockIdx.z;
  const int w = threadIdx.x >> 6, l = threadIdx.x & 63;
  const int l16 = l & 15, lg = l >> 4;
  const float* Xb = X + (size_t)b * 192 * 4096;
  const size_t sstride = (size_t)4 * 192 * 4096;

  f32x4 acc[4] = {f32x4{0,0,0,0}, f32x4{0,0,0,0}, f32x4{0,0,0,0}, f32x4{0,0,0,0}};

  for (int ks = 0; ks < 6; ++ks) {
    const int c0 = ks * 32 + lg * 8;
    bf16x8 a = *(const bf16x8*)(Wp + (size_t)(o0 + 16 * w + l16) * 192 + c0);
#pragma unroll
    for (int n = 0; n < 4; ++n) {
      const int hw = hw0 + 16 * n + l16;
      bf16x8 bfr;
#pragma unroll
      for (int j = 0; j < 8; ++j) {
        float s = Xb[(size_t)(c0 + j) * 4096 + hw];
#pragma unroll
        for (int ss = 1; ss < NS; ++ss)
          s += Xb[(size_t)(c0 + j) * 4096 + hw + ss * sstride];
        bfr[j] = (short)f2bf(s);
      }
      acc[n] = mfma16(a, bfr, acc[n]);
    }
  }

#pragma unroll
  for (int n = 0; n < 4; ++n) {
    const int hw = hw0 + 16 * n + l16;
#pragma unroll
    for (int r = 0; r < 4; ++r) {
      const int o = o0 + 16 * w + lg * 4 + r;
      Yv[((size_t)b * 192 + o) * 4096 + hw] = fmaxf(acc[n][r] + bias[o], 0.0f);
    }
  }
}

// ---------------- pass 1: E = exp2(S) bf16 (materialized) + colsum ----------------
__launch_bounds__(256)
__global__ void pass1_e_kernel(const unsigned short* __restrict__ qp,
                               const unsigned short* __restrict__ kpT,
                               unsigned short* __restrict__ E,
                               float* __restrict__ colsum) {
  const int q0 = blockIdx.x * 128, k0 = blockIdx.y * 128, b = blockIdx.z;
  const int w = threadIdx.x >> 6, l = threadIdx.x & 63;
  const int l16 = l & 15, lg = l >> 4;
  const unsigned short* qb = qp + (size_t)b * 4096 * 192;
  const unsigned short* kb = kpT + (size_t)b * 4096 * 192;

  __shared__ __align__(16) unsigned short smem[128 * 200];  // Q panel, then Et[128][144]

  {  // stage Q panel rows q0..q0+127
    const int t = threadIdx.x;
#pragma unroll
    for (int i = 0; i < 12; ++i) {
      int idx = t + i * 256;
      int row = idx / 24, cu = idx % 24;
      uint4 vdat = *(const uint4*)(qb + (size_t)(q0 + row) * 192 + cu * 8);
      *(uint4*)&smem[row * 200 + cu * 8] = vdat;
    }
  }
  __syncthreads();

  f32x4 acc[2][8];
#pragma unroll
  for (int m = 0; m < 2; ++m)
#pragma unroll
    for (int n = 0; n < 8; ++n) acc[m][n] = f32x4{0, 0, 0, 0};

  for (int ks = 0; ks < 6; ++ks) {
    const int c0 = ks * 32 + lg * 8;
    bf16x8 a0 = *(const bf16x8*)(kb + (size_t)(k0 + 32 * w + l16) * 192 + c0);
    bf16x8 a1 = *(const bf16x8*)(kb + (size_t)(k0 + 32 * w + 16 + l16) * 192 + c0);
#pragma unroll
    for (int n = 0; n < 8; ++n) {
      bf16x8 bfr = *(const bf16x8*)&smem[(16 * n + l16) * 200 + c0];
      acc[0][n] = mfma16(a0, bfr, acc[0][n]);
      acc[1][n] = mfma16(a1, bfr, acc[1][n]);
    }
  }

  // exp2 in place + colsum (sum over q = over n and l16 lanes)
#pragma unroll
  for (int m = 0; m < 2; ++m) {
#pragma unroll
    for (int r = 0; r < 4; ++r) {
      float s = 0.f;
#pragma unroll
      for (int n = 0; n < 8; ++n) {
        float e = __builtin_amdgcn_exp2f(acc[m][n][r]);
        acc[m][n][r] = e;
        s += e;
      }
      s += __shfl_xor(s, 1);
      s += __shfl_xor(s, 2);
      s += __shfl_xor(s, 4);
      s += __shfl_xor(s, 8);
      if (l16 == 0)
        atomicAdd(&colsum[(size_t)b * 4096 + k0 + 32 * w + 16 * m + lg * 4 + r], s);
    }
  }

  __syncthreads();  // Q panel no longer needed -> reuse as Et[128][144]
#pragma unroll
  for (int m = 0; m < 2; ++m)
#pragma unroll
    for (int n = 0; n < 8; ++n) {
      unsigned int lo = (unsigned)f2bf(acc[m][n][0]) | ((unsigned)f2bf(acc[m][n][1]) << 16);
      unsigned int hi = (unsigned)f2bf(acc[m][n][2]) | ((unsigned)f2bf(acc[m][n][3]) << 16);
      uint2 pk; pk.x = lo; pk.y = hi;
      *(uint2*)&smem[(16 * n + l16) * 144 + 32 * w + 16 * m + lg * 4] = pk;
    }
  __syncthreads();

  {  // coalesced E store: 128 rows x 256B
    const int t = threadIdx.x;
#pragma unroll
    for (int i = 0; i < 8; ++i) {
      int idx = t + i * 256;
      int row = idx >> 4, c16 = idx & 15;
      uint4 vdat = *(const uint4*)&smem[row * 144 + c16 * 8];
      *(uint4*)(E + (size_t)(b * 4096 + q0 + row) * 4096 + k0 + c16 * 8) = vdat;
    }
  }
}

__global__ void invert_kernel(float* __restrict__ p, int n) {
  int i = blockIdx.x * 256 + threadIdx.x;
  if (i < n) p[i] = 1.0f / p[i];
}

// ---------------- vscale: vps[b][c][k] = vp[b][c][k] * rcol[b][k] ----------------
__launch_bounds__(256)
__global__ void vscale_kernel(const unsigned short* __restrict__ vp,
                              const float* __restrict__ rcol,
                              unsigned short* __restrict__ vps) {
  int i = blockIdx.x * 256 + threadIdx.x;  // 393216 chunks of 8
  if (i >= 4 * 192 * 512) return;
  int b = i / (192 * 512);
  int k = (i & 511) * 8;
  f32x4 rc0 = *(const f32x4*)(rcol + b * 4096 + k);
  f32x4 rc1 = *(const f32x4*)(rcol + b * 4096 + k + 4);
  bf16x8 v = *(const bf16x8*)(vp + (size_t)i * 8);
  bf16x8 o;
#pragma unroll
  for (int j = 0; j < 4; ++j) {
    o[j] = (short)f2bf(bf2f((unsigned short)v[j]) * rc0[j]);
    o[j + 4] = (short)f2bf(bf2f((unsigned short)v[j + 4]) * rc1[j]);
  }
  *(bf16x8*)(vps + (size_t)i * 8) = o;
}

// ---------------- pv: ss = E @ V' — double-buffered async LDS + counted vmcnt ----------------
// M-tile 128, 512 threads (8 waves x 16q x 192c), K-chunks of 64, NS=4 k-split.
// T3/T4: chunk k+1's 5 global_load_lds are issued into buffer B BEFORE chunk k's
// MFMA on buffer A; leading wait is vmcnt(5) (own chunk-k loads done; k+1 loads
// stay in flight under MFMA), never vmcnt(0) mid-loop. Raw s_barrier +
// sched_barrier(0) per rule #18. Trailing lgkmcnt(0)+barrier protects buffer
// reuse (overwritten 2 iterations later). Swizzle on global source per rule #21.
__launch_bounds__(512)
__global__ void pv_kernel(const unsigned short* __restrict__ E,
                          const unsigned short* __restrict__ vps,
                          float* __restrict__ ssP) {
  const int q0 = blockIdx.x * 128;
  const int s = blockIdx.y;
  const int b = blockIdx.z;
  const int w = threadIdx.x >> 6, l = threadIdx.x & 63;
  const int l16 = l & 15, lg = l >> 4;
  const unsigned short* Eb = E + (size_t)b * 4096 * 4096;
  const unsigned short* vb = vps + (size_t)b * 192 * 4096;
  float* ssb = ssP + (size_t)(s * 4 + b) * 192 * 4096;

  __shared__ __align__(16) unsigned short Est[2][128][64];  // 32 KB
  __shared__ __align__(16) unsigned short Vst[2][192][64];  // 48 KB

  const int t = threadIdx.x;
  const int srow = t >> 3;                    // staging row within 64-row tile
  const int gc8 = (t & 7) ^ (srow & 7);       // pre-swizzled global 16B-group
  const int rs = l16 & 7;                     // read-side row XOR term

  f32x4 ssa[12];
#pragma unroll
  for (int j = 0; j < 12; ++j) ssa[j] = f32x4{0, 0, 0, 0};

  const int kc0 = s * 16;  // NS=4 -> 16 chunks of 64

#define PV_ISSUE(KC, BUF)                                                              \
  do {                                                                                 \
    const int k0_ = (KC) * 64;                                                         \
    _Pragma("unroll")                                                                  \
    for (int i = 0; i < 2; ++i) {                                                      \
      const unsigned short* src = Eb + (size_t)(q0 + i * 64 + srow) * 4096 + k0_ + gc8 * 8; \
      __builtin_amdgcn_global_load_lds(                                                \
          (gbl_void*)src,                                                              \
          (lds_void*)((char*)&Est[BUF][0][0] + i * 8192 + w * 1024), 16, 0, 0);        \
    }                                                                                  \
    _Pragma("unroll")                                                                  \
    for (int i = 0; i < 3; ++i) {                                                      \
      const unsigned short* src = vb + (size_t)(i * 64 + srow) * 4096 + k0_ + gc8 * 8; \
      __builtin_amdgcn_global_load_lds(                                                \
          (gbl_void*)src,                                                              \
          (lds_void*)((char*)&Vst[BUF][0][0] + i * 8192 + w * 1024), 16, 0, 0);        \
    }                                                                                  \
  } while (0)

  PV_ISSUE(kc0, 0);

  for (int kc = kc0; kc < kc0 + 16; ++kc) {
    const int cur = (kc - kc0) & 1;
    const bool havenext = (kc + 1 < kc0 + 16);

    if (havenext) PV_ISSUE(kc + 1, cur ^ 1);

    // wait own chunk-kc loads (5 newer in flight if issued); barrier -> all waves' data in LDS
    if (havenext)
      asm volatile("s_waitcnt vmcnt(5)" ::: "memory");
    else
      asm volatile("s_waitcnt vmcnt(0)" ::: "memory");
    __builtin_amdgcn_s_barrier();
    __builtin_amdgcn_sched_barrier(0);

    // MFMA: wave tile 16q x 192c over K=64 (swizzled reads) — next-chunk loads in flight
#pragma unroll
    for (int kstep = 0; kstep < 2; ++kstep) {
      const int gcol = ((kstep * 4 + lg) ^ rs) * 8;
      bf16x8 af = *(const bf16x8*)&Est[cur][16 * w + l16][gcol];
#pragma unroll
      for (int j = 0; j < 12; ++j) {
        bf16x8 bfr = *(const bf16x8*)&Vst[cur][16 * j + l16][gcol];
        ssa[j] = mfma16(af, bfr, ssa[j]);
      }
    }

    // all waves done reading buf cur before it is overwritten (2 iters later)
    asm volatile("s_waitcnt lgkmcnt(0)" ::: "memory");
    __builtin_amdgcn_s_barrier();
    __builtin_amdgcn_sched_barrier(0);
  }
#undef PV_ISSUE

  // ssa[j][r] = ss[q0+16w+lg*4+r][16j+l16] -> slab [c][q] f32x4 stores along q
#pragma unroll
  for (int j = 0; j < 12; ++j)
    *(f32x4*)(ssb + (size_t)(16 * j + l16) * 4096 + q0 + 16 * w + lg * 4) = ssa[j];
}

// ---------------- corr: pure streaming corr = f32(E) * rcol ----------------
__launch_bounds__(256)
__global__ void corr_kernel(const unsigned short* __restrict__ E,
                            const float* __restrict__ rcol,
                            float* __restrict__ corr) {
  const size_t N = (size_t)4 * 4096 * 512;  // 8-element chunks
  for (size_t i = (size_t)blockIdx.x * 256 + threadIdx.x; i < N; i += (size_t)gridDim.x * 256) {
    size_t bq = i >> 9;
    int k = ((int)i & 511) * 8;
    int b = (int)(bq >> 12);
    bf16x8 e = *(const bf16x8*)(E + bq * 4096 + k);
    f32x4 rc0 = *(const f32x4*)(rcol + b * 4096 + k);
    f32x4 rc1 = *(const f32x4*)(rcol + b * 4096 + k + 4);
    f32x4 o0, o1;
#pragma unroll
    for (int j = 0; j < 4; ++j) {
      o0[j] = bf2f((unsigned short)e[j]) * rc0[j];
      o1[j] = bf2f((unsigned short)e[j + 4]) * rc1[j];
    }
    __builtin_nontemporal_store(o0, (f32x4*)(corr + bq * 4096 + k));
    __builtin_nontemporal_store(o1, (f32x4*)(corr + bq * 4096 + k + 4));
  }
}

// ================= FALLBACK (round-6 proven path) =================
__launch_bounds__(256)
__global__ void pass1_basic_kernel(const unsigned short* __restrict__ qp,
                                   const unsigned short* __restrict__ kpT,
                                   float* __restrict__ colsum) {
  const int q0 = blockIdx.x * 128, k0 = blockIdx.y * 128, b = blockIdx.z;
  const int w = threadIdx.x >> 6, l = threadIdx.x & 63;
  const int l16 = l & 15, lg = l >> 4;
  const unsigned short* qb = qp + (size_t)b * 4096 * 192;
  const unsigned short* kb = kpT + (size_t)b * 4096 * 192;

  __shared__ __align__(16) unsigned short kpl[128][200];
  __shared__ float cs[4][128];

  {
    const int t = threadIdx.x;
#pragma unroll
    for (int i = 0; i < 12; ++i) {
      int idx = t + i * 256;
      int row = idx / 24, cu = idx % 24;
      uint4 vdat = *(const uint4*)(kb + (size_t)(k0 + row) * 192 + cu * 8);
      *(uint4*)&kpl[row][cu * 8] = vdat;
    }
  }
  __syncthreads();

  f32x4 acc[2][8];
#pragma unroll
  for (int m = 0; m < 2; ++m)
#pragma unroll
    for (int n = 0; n < 8; ++n) acc[m][n] = f32x4{0, 0, 0, 0};

  for (int ks = 0; ks < 6; ++ks) {
    const int c0 = ks * 32 + lg * 8;
    bf16x8 a0 = *(const bf16x8*)(qb + (size_t)(q0 + 32 * w + l16) * 192 + c0);
    bf16x8 a1 = *(const bf16x8*)(qb + (size_t)(q0 + 32 * w + 16 + l16) * 192 + c0);
#pragma unroll
    for (int n = 0; n < 8; ++n) {
      bf16x8 bfr = *(const bf16x8*)&kpl[16 * n + l16][c0];
      acc[0][n] = mfma16(a0, bfr, acc[0][n]);
      acc[1][n] = mfma16(a1, bfr, acc[1][n]);
    }
  }

  float part[8];
#pragma unroll
  for (int n = 0; n < 8; ++n) {
    float s = 0.f;
#pragma unroll
    for (int r = 0; r < 4; ++r)
      s += __builtin_amdgcn_exp2f(acc[0][n][r]) + __builtin_amdgcn_exp2f(acc[1][n][r]);
    s += __shfl_xor(s, 16);
    s += __shfl_xor(s, 32);
    part[n] = s;
  }
  if (l < 16) {
#pragma unroll
    for (int n = 0; n < 8; ++n) cs[w][16 * n + l] = part[n];
  }
  __syncthreads();
  const int t = threadIdx.x;
  if (t < 128) {
    float s = cs[0][t] + cs[1][t] + cs[2][t] + cs[3][t];
    atomicAdd(&colsum[(size_t)b * 4096 + k0 + t], s);
  }
}

template <int NS>
__launch_bounds__(512)
__global__ void pass2_basic_kernel(const unsigned short* __restrict__ qp,
                                   const unsigned short* __restrict__ kpT,
                                   const unsigned short* __restrict__ vpN,
                                   const float* __restrict__ rcol,
                                   float* __restrict__ corr,
                                   float* __restrict__ ssP) {
  const int q0 = blockIdx.x * 64;
  const int s = blockIdx.y;
  const int b = blockIdx.z;
  const int kc0 = s * (32 / NS);
  const int w = threadIdx.x >> 6, l = threadIdx.x & 63;
  const int l16 = l & 15, lg = l >> 4;
  const int mw = w & 1, nw = w >> 1;
  const unsigned short* qb = qp + (size_t)b * 4096 * 192;
  const unsigned short* kb = kpT + (size_t)b * 4096 * 192;
  const unsigned short* vb = vpN + (size_t)b * 192 * 4096;
  const float* rc = rcol + (size_t)b * 4096;
  float* corb = corr + (size_t)b * 4096 * 4096;
  float* ssb = ssP + (size_t)(s * 4 + b) * 192 * 4096;

  __shared__ __align__(16) float cor[64][132];

  bf16x8 af[2][6];
#pragma unroll
  for (int tm = 0; tm < 2; ++tm)
#pragma unroll
    for (int ks = 0; ks < 6; ++ks)
      af[tm][ks] = *(const bf16x8*)(qb + (size_t)(q0 + 16 * (2 * mw + tm) + l16) * 192 + ks * 32 + lg * 8);

  f32x4 ssa[2][3];
#pragma unroll
  for (int tm = 0; tm < 2; ++tm)
#pragma unroll
    for (int j = 0; j < 3; ++j) ssa[tm][j] = f32x4{0, 0, 0, 0};

  for (int kc = kc0; kc < kc0 + 32 / NS; ++kc) {
    const int k0 = kc * 128;
    f32x4 sa[2][2];
#pragma unroll
    for (int tm = 0; tm < 2; ++tm)
#pragma unroll
      for (int tn = 0; tn < 2; ++tn) sa[tm][tn] = f32x4{0, 0, 0, 0};

    for (int ks = 0; ks < 6; ++ks) {
      const int c0 = ks * 32 + lg * 8;
#pragma unroll
      for (int tn = 0; tn < 2; ++tn) {
        const int kcol = k0 + 16 * (2 * nw + tn) + l16;
        bf16x8 bfr = *(const bf16x8*)(kb + (size_t)kcol * 192 + c0);
        sa[0][tn] = mfma16(af[0][ks], bfr, sa[0][tn]);
        sa[1][tn] = mfma16(af[1][ks], bfr, sa[1][tn]);
      }
    }
    float rcv[2];
#pragma unroll
    for (int tn = 0; tn < 2; ++tn) rcv[tn] = rc[k0 + 16 * (2 * nw + tn) + l16];
#pragma unroll
    for (int tm = 0; tm < 2; ++tm)
#pragma unroll
      for (int tn = 0; tn < 2; ++tn)
#pragma unroll
        for (int r = 0; r < 4; ++r)
          sa[tm][tn][r] = __builtin_amdgcn_exp2f(sa[tm][tn][r]) * rcv[tn];

    __syncthreads();
#pragma unroll
    for (int tm = 0; tm < 2; ++tm)
#pragma unroll
      for (int tn = 0; tn < 2; ++tn) {
        const int col = 16 * (2 * nw + tn) + l16;
#pragma unroll
        for (int r = 0; r < 4; ++r)
          cor[16 * (2 * mw + tm) + lg * 4 + r][col] = sa[tm][tn][r];
      }
    __syncthreads();

    {
      const int t = threadIdx.x;
#pragma unroll
      for (int it = 0; it < 4; ++it) {
        int idx = t + it * 512;
        int row = idx >> 5, seg = idx & 31;
        f32x4 v4 = *(const f32x4*)&cor[row][seg * 4];
        __builtin_nontemporal_store(v4, (f32x4*)(corb + (size_t)(q0 + row) * 4096 + k0 + seg * 4));
      }
    }

#pragma unroll
    for (int ks2 = 0; ks2 < 4; ++ks2) {
      const int cc = ks2 * 32 + lg * 8;
      bf16x8 pa[2];
#pragma unroll
      for (int tm = 0; tm < 2; ++tm) {
        f32x4 p0 = *(const f32x4*)&cor[16 * (2 * mw + tm) + l16][cc];
        f32x4 p1 = *(const f32x4*)&cor[16 * (2 * mw + tm) + l16][cc + 4];
#pragma unroll
        for (int j = 0; j < 4; ++j) {
          pa[tm][j] = (short)f2bf(p0[j]);
          pa[tm][j + 4] = (short)f2bf(p1[j]);
        }
      }
#pragma unroll
      for (int j = 0; j < 3; ++j) {
        const int ccol = 16 * (nw + 4 * j) + l16;
        bf16x8 bfr = *(const bf16x8*)(vb + (size_t)ccol * 4096 + k0 + cc);
        ssa[0][j] = mfma16(pa[0], bfr, ssa[0][j]);
        ssa[1][j] = mfma16(pa[1], bfr, ssa[1][j]);
      }
    }
  }

#pragma unroll
  for (int tm = 0; tm < 2; ++tm)
#pragma unroll
    for (int j = 0; j < 3; ++j) {
      const int ccol = 16 * (nw + 4 * j) + l16;
#pragma unroll
      for (int r = 0; r < 4; ++r) {
        const int qrow = q0 + 16 * (2 * mw + tm) + lg * 4 + r;
        ssb[(size_t)ccol * 4096 + qrow] = ssa[tm][j][r];
      }
    }
}

// ---------------- launcher ----------------
extern "C" void kernel_launch(void* const* d_in, const int* in_sizes, int n_in,
                              void* d_out, int out_size, void* d_ws, size_t ws_size,
                              hipStream_t stream) {
  (void)in_sizes; (void)n_in; (void)out_size;
  const float* lr = (const float*)d_in[0];
  const float* refine = (const float*)d_in[1];

  char* ws = (char*)d_ws;
  unsigned short* w4 = (unsigned short*)(ws + 0);                       // [0, 294912)
  float* bias4 = (float*)(ws + 294912);                                // [294912, 297984)
  unsigned short* qp = (unsigned short*)(ws + 297984);                 // 6291456 B
  unsigned short* kp = (unsigned short*)(ws + 297984 + 6291456);       // 6291456 B
  unsigned short* vp = (unsigned short*)(ws + 297984 + 2 * 6291456);   // 6291456 B -> ends 19172352
  float* colsum = (float*)(ws + 19172352);                             // 65536 B -> ends 19237888
  unsigned short* vps = (unsigned short*)(ws + 19237888);              // 6291456 B -> ends 25529344
  float* ssP = (float*)(ws + 25529344);                                // 4 slabs x 12582912 -> ends 75860992
  unsigned short* Ebuf = (unsigned short*)(ws + 75860992);             // 134217728 B -> ends 210078720
  const size_t NEW_NEED = 210078720;

  float* out0 = (float*)d_out;
  float* corr = out0 + 3145728;  // [4][4096][4096] f32

  const float alpha = (float)(1.4426950408889634 / sqrt(192.0));  // log2(e)/sqrt(C)

  for (int p = 0; p < 4; ++p) {
    prep_kernel<<<dim3(144), dim3(256), 0, stream>>>(
        (const float*)d_in[2 + 5 * p], (const float*)d_in[3 + 5 * p],
        (const float*)d_in[4 + 5 * p], (const float*)d_in[5 + 5 * p],
        (const float*)d_in[6 + 5 * p],
        w4 + p * 36864, bias4 + p * 192, p == 0 ? alpha : 1.0f);
  }
  hipMemsetAsync(colsum, 0, 65536, stream);

  proj_kernel<1><<<dim3(3, 64, 4), dim3(256), 0, stream>>>(refine, w4, bias4, qp);
  proj_kernel<1><<<dim3(3, 64, 4), dim3(256), 0, stream>>>(lr, w4 + 36864, bias4 + 192, kp);
  proj_kernel<0><<<dim3(3, 64, 4), dim3(256), 0, stream>>>(lr, w4 + 2 * 36864, bias4 + 2 * 192, vp);

  if (ws_size >= NEW_NEED) {
    // ---- E-materialization path ----
    pass1_e_kernel<<<dim3(32, 32, 4), dim3(256), 0, stream>>>(qp, kp, Ebuf, colsum);
    invert_kernel<<<dim3(64), dim3(256), 0, stream>>>(colsum, 16384);
    vscale_kernel<<<dim3(1536), dim3(256), 0, stream>>>(vp, colsum, vps);
    pv_kernel<<<dim3(32, 4, 4), dim3(512), 0, stream>>>(Ebuf, vps, ssP);
    proj_sum_kernel<4><<<dim3(3, 64, 4), dim3(256), 0, stream>>>(ssP, w4 + 3 * 36864, bias4 + 3 * 192, out0);
    corr_kernel<<<dim3(2048), dim3(256), 0, stream>>>(Ebuf, colsum, corr);
  } else {
    // ---- fallback: round-6 proven path (NS=2) ----
    pass1_basic_kernel<<<dim3(32, 32, 4), dim3(256), 0, stream>>>(qp, kp, colsum);
    invert_kernel<<<dim3(64), dim3(256), 0, stream>>>(colsum, 16384);
    pass2_basic_kernel<2><<<dim3(64, 2, 4), dim3(512), 0, stream>>>(qp, kp, vp, colsum, corr, ssP);
    proj_sum_kernel<2><<<dim3(3, 64, 4), dim3(256), 0, stream>>>(ssP, w4 + 3 * 36864, bias4 + 3 * 192, out0);
  }
}

// Round 22
// 259.501 us; speedup vs baseline: 1.0269x; 1.0269x over previous
//
#include <hip/hip_runtime.h>
#include <math.h>

typedef __attribute__((ext_vector_type(4))) float f32x4;
typedef __attribute__((ext_vector_type(8))) short bf16x8;

typedef __attribute__((address_space(3))) void lds_void;
typedef const __attribute__((address_space(1))) void gbl_void;

__device__ __forceinline__ unsigned short f2bf(float f) {
  unsigned int u = __builtin_bit_cast(unsigned int, f);
  u += 0x7FFFu + ((u >> 16) & 1u);
  return (unsigned short)(u >> 16);
}

__device__ __forceinline__ float bf2f(unsigned short u) {
  return __builtin_bit_cast(float, (unsigned int)u << 16);
}

__device__ __forceinline__ f32x4 mfma16(bf16x8 a, bf16x8 b, f32x4 c) {
  return __builtin_amdgcn_mfma_f32_16x16x32_bf16(a, b, c, 0, 0, 0);
}

struct PrepArgs {
  const float* W[4];
  const float* g[4];
  const float* bb[4];
  const float* mm[4];
  const float* vv[4];
};

// ---------------- prep (all 4 projections in one launch): fold BN into W + bias ----------------
__global__ void prep_all_kernel(PrepArgs pa, unsigned short* __restrict__ Wout,
                                float* __restrict__ bout, float alpha0) {
  const int p = blockIdx.y;
  const float alpha = (p == 0) ? alpha0 : 1.0f;
  int idx = blockIdx.x * 256 + threadIdx.x;
  if (idx < 192 * 192) {
    int o = idx / 192;
    float s = pa.g[p][o] * rsqrtf(pa.vv[p][o] + 1e-5f);
    Wout[p * 36864 + idx] = f2bf(pa.W[p][idx] * s * alpha);
  }
  if (idx < 192) {
    float s = pa.g[p][idx] * rsqrtf(pa.vv[p][idx] + 1e-5f);
    bout[p * 192 + idx] = (pa.bb[p][idx] - pa.mm[p][idx] * s) * alpha;
  }
}

// ---------------- projection: Y = relu(W' X + bias) ----------------
template <int LAYOUT>
__launch_bounds__(256)
__global__ void proj_kernel(const float* __restrict__ X,
                            const unsigned short* __restrict__ Wp,
                            const float* __restrict__ bias,
                            unsigned short* __restrict__ Yv) {
  const int o0 = blockIdx.x * 64;
  const int hw0 = blockIdx.y * 64;
  const int b = blockIdx.z;
  const int w = threadIdx.x >> 6, l = threadIdx.x & 63;
  const int l16 = l & 15, lg = l >> 4;
  const float* Xb = X + (size_t)b * 192 * 4096;

  f32x4 acc[4] = {f32x4{0,0,0,0}, f32x4{0,0,0,0}, f32x4{0,0,0,0}, f32x4{0,0,0,0}};

  for (int ks = 0; ks < 6; ++ks) {
    const int c0 = ks * 32 + lg * 8;
    bf16x8 a = *(const bf16x8*)(Wp + (size_t)(o0 + 16 * w + l16) * 192 + c0);
#pragma unroll
    for (int n = 0; n < 4; ++n) {
      const int hw = hw0 + 16 * n + l16;
      bf16x8 bfr;
#pragma unroll
      for (int j = 0; j < 8; ++j)
        bfr[j] = (short)f2bf(Xb[(size_t)(c0 + j) * 4096 + hw]);
      acc[n] = mfma16(a, bfr, acc[n]);
    }
  }

#pragma unroll
  for (int n = 0; n < 4; ++n) {
    const int hw = hw0 + 16 * n + l16;
    float vv4[4];
#pragma unroll
    for (int r = 0; r < 4; ++r) {
      const int o = o0 + 16 * w + lg * 4 + r;
      vv4[r] = fmaxf(acc[n][r] + bias[o], 0.0f);
    }
    if (LAYOUT == 1) {
      unsigned int lo = (unsigned)f2bf(vv4[0]) | ((unsigned)f2bf(vv4[1]) << 16);
      unsigned int hi = (unsigned)f2bf(vv4[2]) | ((unsigned)f2bf(vv4[3]) << 16);
      uint2 pk; pk.x = lo; pk.y = hi;
      *(uint2*)(Yv + ((size_t)b * 4096 + hw) * 192 + o0 + 16 * w + lg * 4) = pk;
    } else {
#pragma unroll
      for (int r = 0; r < 4; ++r) {
        const int o = o0 + 16 * w + lg * 4 + r;
        Yv[((size_t)b * 192 + o) * 4096 + hw] = f2bf(vv4[r]);
      }
    }
  }
}

// ---------------- final projection with NS-way partial-sum input (f32 out) ----------------
template <int NS>
__launch_bounds__(256)
__global__ void proj_sum_kernel(const float* __restrict__ X,
                                const unsigned short* __restrict__ Wp,
                                const float* __restrict__ bias,
                                float* __restrict__ Yv) {
  const int o0 = blockIdx.x * 64;
  const int hw0 = blockIdx.y * 64;
  const int b = blockIdx.z;
  const int w = threadIdx.x >> 6, l = threadIdx.x & 63;
  const int l16 = l & 15, lg = l >> 4;
  const float* Xb = X + (size_t)b * 192 * 4096;
  const size_t sstride = (size_t)4 * 192 * 4096;

  f32x4 acc[4] = {f32x4{0,0,0,0}, f32x4{0,0,0,0}, f32x4{0,0,0,0}, f32x4{0,0,0,0}};

  for (int ks = 0; ks < 6; ++ks) {
    const int c0 = ks * 32 + lg * 8;
    bf16x8 a = *(const bf16x8*)(Wp + (size_t)(o0 + 16 * w + l16) * 192 + c0);
#pragma unroll
    for (int n = 0; n < 4; ++n) {
      const int hw = hw0 + 16 * n + l16;
      bf16x8 bfr;
#pragma unroll
      for (int j = 0; j < 8; ++j) {
        float s = Xb[(size_t)(c0 + j) * 4096 + hw];
#pragma unroll
        for (int ss = 1; ss < NS; ++ss)
          s += Xb[(size_t)(c0 + j) * 4096 + hw + ss * sstride];
        bfr[j] = (short)f2bf(s);
      }
      acc[n] = mfma16(a, bfr, acc[n]);
    }
  }

#pragma unroll
  for (int n = 0; n < 4; ++n) {
    const int hw = hw0 + 16 * n + l16;
#pragma unroll
    for (int r = 0; r < 4; ++r) {
      const int o = o0 + 16 * w + lg * 4 + r;
      Yv[((size_t)b * 192 + o) * 4096 + hw] = fmaxf(acc[n][r] + bias[o], 0.0f);
    }
  }
}

// ---------------- pass 1: E = exp2(S) bf16 (materialized) + colsum ----------------
__launch_bounds__(256)
__global__ void pass1_e_kernel(const unsigned short* __restrict__ qp,
                               const unsigned short* __restrict__ kpT,
                               unsigned short* __restrict__ E,
                               float* __restrict__ colsum) {
  const int q0 = blockIdx.x * 128, k0 = blockIdx.y * 128, b = blockIdx.z;
  const int w = threadIdx.x >> 6, l = threadIdx.x & 63;
  const int l16 = l & 15, lg = l >> 4;
  const unsigned short* qb = qp + (size_t)b * 4096 * 192;
  const unsigned short* kb = kpT + (size_t)b * 4096 * 192;

  __shared__ __align__(16) unsigned short smem[128 * 200];  // Q panel, then Et[128][144]

  {  // stage Q panel rows q0..q0+127
    const int t = threadIdx.x;
#pragma unroll
    for (int i = 0; i < 12; ++i) {
      int idx = t + i * 256;
      int row = idx / 24, cu = idx % 24;
      uint4 vdat = *(const uint4*)(qb + (size_t)(q0 + row) * 192 + cu * 8);
      *(uint4*)&smem[row * 200 + cu * 8] = vdat;
    }
  }
  __syncthreads();

  f32x4 acc[2][8];
#pragma unroll
  for (int m = 0; m < 2; ++m)
#pragma unroll
    for (int n = 0; n < 8; ++n) acc[m][n] = f32x4{0, 0, 0, 0};

  for (int ks = 0; ks < 6; ++ks) {
    const int c0 = ks * 32 + lg * 8;
    bf16x8 a0 = *(const bf16x8*)(kb + (size_t)(k0 + 32 * w + l16) * 192 + c0);
    bf16x8 a1 = *(const bf16x8*)(kb + (size_t)(k0 + 32 * w + 16 + l16) * 192 + c0);
#pragma unroll
    for (int n = 0; n < 8; ++n) {
      bf16x8 bfr = *(const bf16x8*)&smem[(16 * n + l16) * 200 + c0];
      acc[0][n] = mfma16(a0, bfr, acc[0][n]);
      acc[1][n] = mfma16(a1, bfr, acc[1][n]);
    }
  }

  // exp2 in place + colsum (sum over q = over n and l16 lanes)
#pragma unroll
  for (int m = 0; m < 2; ++m) {
#pragma unroll
    for (int r = 0; r < 4; ++r) {
      float s = 0.f;
#pragma unroll
      for (int n = 0; n < 8; ++n) {
        float e = __builtin_amdgcn_exp2f(acc[m][n][r]);
        acc[m][n][r] = e;
        s += e;
      }
      s += __shfl_xor(s, 1);
      s += __shfl_xor(s, 2);
      s += __shfl_xor(s, 4);
      s += __shfl_xor(s, 8);
      if (l16 == 0)
        atomicAdd(&colsum[(size_t)b * 4096 + k0 + 32 * w + 16 * m + lg * 4 + r], s);
    }
  }

  __syncthreads();  // Q panel no longer needed -> reuse as Et[128][144]
#pragma unroll
  for (int m = 0; m < 2; ++m)
#pragma unroll
    for (int n = 0; n < 8; ++n) {
      unsigned int lo = (unsigned)f2bf(acc[m][n][0]) | ((unsigned)f2bf(acc[m][n][1]) << 16);
      unsigned int hi = (unsigned)f2bf(acc[m][n][2]) | ((unsigned)f2bf(acc[m][n][3]) << 16);
      uint2 pk; pk.x = lo; pk.y = hi;
      *(uint2*)&smem[(16 * n + l16) * 144 + 32 * w + 16 * m + lg * 4] = pk;
    }
  __syncthreads();

  {  // coalesced E store: 128 rows x 256B
    const int t = threadIdx.x;
#pragma unroll
    for (int i = 0; i < 8; ++i) {
      int idx = t + i * 256;
      int row = idx >> 4, c16 = idx & 15;
      uint4 vdat = *(const uint4*)&smem[row * 144 + c16 * 8];
      *(uint4*)(E + (size_t)(b * 4096 + q0 + row) * 4096 + k0 + c16 * 8) = vdat;
    }
  }
}

__global__ void invert_kernel(float* __restrict__ p, int n) {
  int i = blockIdx.x * 256 + threadIdx.x;
  if (i < n) p[i] = 1.0f / p[i];
}

// ---------------- vscale: vps[b][c][k] = vp[b][c][k] / colsum[b][k] (inline rcp) ----------------
__launch_bounds__(256)
__global__ void vscale_kernel(const unsigned short* __restrict__ vp,
                              const float* __restrict__ colsum,
                              unsigned short* __restrict__ vps) {
  int i = blockIdx.x * 256 + threadIdx.x;  // 393216 chunks of 8
  if (i >= 4 * 192 * 512) return;
  int b = i / (192 * 512);
  int k = (i & 511) * 8;
  f32x4 cs0 = *(const f32x4*)(colsum + b * 4096 + k);
  f32x4 cs1 = *(const f32x4*)(colsum + b * 4096 + k + 4);
  bf16x8 v = *(const bf16x8*)(vp + (size_t)i * 8);
  bf16x8 o;
#pragma unroll
  for (int j = 0; j < 4; ++j) {
    o[j] = (short)f2bf(bf2f((unsigned short)v[j]) / cs0[j]);
    o[j + 4] = (short)f2bf(bf2f((unsigned short)v[j + 4]) / cs1[j]);
  }
  *(bf16x8*)(vps + (size_t)i * 8) = o;
}

// ---------------- pv: ss = E @ V' — swizzled LDS + async global_load_lds (r20 best) ----------------
__launch_bounds__(512)
__global__ void pv_kernel(const unsigned short* __restrict__ E,
                          const unsigned short* __restrict__ vps,
                          float* __restrict__ ssP) {
  const int q0 = blockIdx.x * 128;
  const int s = blockIdx.y;
  const int b = blockIdx.z;
  const int w = threadIdx.x >> 6, l = threadIdx.x & 63;
  const int l16 = l & 15, lg = l >> 4;
  const unsigned short* Eb = E + (size_t)b * 4096 * 4096;
  const unsigned short* vb = vps + (size_t)b * 192 * 4096;
  float* ssb = ssP + (size_t)(s * 4 + b) * 192 * 4096;

  __shared__ __align__(16) unsigned short Est[128][64];  // 16 KB, swizzled via source
  __shared__ __align__(16) unsigned short Vst[192][64];  // 24 KB, swizzled via source

  const int t = threadIdx.x;
  const int srow = t >> 3;                    // staging row within 64-row tile
  const int gc8 = (t & 7) ^ (srow & 7);       // pre-swizzled global 16B-group
  const int rs = l16 & 7;                     // read-side row XOR term

  f32x4 ssa[12];
#pragma unroll
  for (int j = 0; j < 12; ++j) ssa[j] = f32x4{0, 0, 0, 0};

  const int kc0 = s * 16;  // NS=4 -> 16 chunks of 64
  for (int kc = kc0; kc < kc0 + 16; ++kc) {
    const int k0 = kc * 64;
    {  // async stage: E 128 rows (2 tiles of 64) + V' 192 rows (3 tiles of 64)
#pragma unroll
      for (int i = 0; i < 2; ++i) {
        const int row = i * 64 + srow;
        const unsigned short* src = Eb + (size_t)(q0 + row) * 4096 + k0 + gc8 * 8;
        __builtin_amdgcn_global_load_lds(
            (gbl_void*)src,
            (lds_void*)((char*)&Est[0][0] + i * 8192 + w * 1024), 16, 0, 0);
      }
#pragma unroll
      for (int i = 0; i < 3; ++i) {
        const int row = i * 64 + srow;
        const unsigned short* src = vb + (size_t)row * 4096 + k0 + gc8 * 8;
        __builtin_amdgcn_global_load_lds(
            (gbl_void*)src,
            (lds_void*)((char*)&Vst[0][0] + i * 8192 + w * 1024), 16, 0, 0);
      }
    }
    __syncthreads();  // vmcnt(0) drain completes the direct-to-LDS loads
#pragma unroll
    for (int kstep = 0; kstep < 2; ++kstep) {
      const int gcol = ((kstep * 4 + lg) ^ rs) * 8;
      bf16x8 af = *(const bf16x8*)&Est[16 * w + l16][gcol];
#pragma unroll
      for (int j = 0; j < 12; ++j) {
        bf16x8 bfr = *(const bf16x8*)&Vst[16 * j + l16][gcol];
        ssa[j] = mfma16(af, bfr, ssa[j]);
      }
    }
    __syncthreads();
  }

  // ssa[j][r] = ss[q0+16w+lg*4+r][16j+l16] -> slab [c][q] f32x4 stores along q
#pragma unroll
  for (int j = 0; j < 12; ++j)
    *(f32x4*)(ssb + (size_t)(16 * j + l16) * 4096 + q0 + 16 * w + lg * 4) = ssa[j];
}

// ---------------- corr: pure streaming corr = f32(E) / colsum (inline rcp) ----------------
__launch_bounds__(256)
__global__ void corr_kernel(const unsigned short* __restrict__ E,
                            const float* __restrict__ colsum,
                            float* __restrict__ corr) {
  const size_t N = (size_t)4 * 4096 * 512;  // 8-element chunks
  for (size_t i = (size_t)blockIdx.x * 256 + threadIdx.x; i < N; i += (size_t)gridDim.x * 256) {
    size_t bq = i >> 9;
    int k = ((int)i & 511) * 8;
    int b = (int)(bq >> 12);
    bf16x8 e = *(const bf16x8*)(E + bq * 4096 + k);
    f32x4 cs0 = *(const f32x4*)(colsum + b * 4096 + k);
    f32x4 cs1 = *(const f32x4*)(colsum + b * 4096 + k + 4);
    f32x4 o0, o1;
#pragma unroll
    for (int j = 0; j < 4; ++j) {
      o0[j] = bf2f((unsigned short)e[j]) / cs0[j];
      o1[j] = bf2f((unsigned short)e[j + 4]) / cs1[j];
    }
    __builtin_nontemporal_store(o0, (f32x4*)(corr + bq * 4096 + k));
    __builtin_nontemporal_store(o1, (f32x4*)(corr + bq * 4096 + k + 4));
  }
}

// ================= FALLBACK (round-6 proven path) =================
__launch_bounds__(256)
__global__ void pass1_basic_kernel(const unsigned short* __restrict__ qp,
                                   const unsigned short* __restrict__ kpT,
                                   float* __restrict__ colsum) {
  const int q0 = blockIdx.x * 128, k0 = blockIdx.y * 128, b = blockIdx.z;
  const int w = threadIdx.x >> 6, l = threadIdx.x & 63;
  const int l16 = l & 15, lg = l >> 4;
  const unsigned short* qb = qp + (size_t)b * 4096 * 192;
  const unsigned short* kb = kpT + (size_t)b * 4096 * 192;

  __shared__ __align__(16) unsigned short kpl[128][200];
  __shared__ float cs[4][128];

  {
    const int t = threadIdx.x;
#pragma unroll
    for (int i = 0; i < 12; ++i) {
      int idx = t + i * 256;
      int row = idx / 24, cu = idx % 24;
      uint4 vdat = *(const uint4*)(kb + (size_t)(k0 + row) * 192 + cu * 8);
      *(uint4*)&kpl[row][cu * 8] = vdat;
    }
  }
  __syncthreads();

  f32x4 acc[2][8];
#pragma unroll
  for (int m = 0; m < 2; ++m)
#pragma unroll
    for (int n = 0; n < 8; ++n) acc[m][n] = f32x4{0, 0, 0, 0};

  for (int ks = 0; ks < 6; ++ks) {
    const int c0 = ks * 32 + lg * 8;
    bf16x8 a0 = *(const bf16x8*)(qb + (size_t)(q0 + 32 * w + l16) * 192 + c0);
    bf16x8 a1 = *(const bf16x8*)(qb + (size_t)(q0 + 32 * w + 16 + l16) * 192 + c0);
#pragma unroll
    for (int n = 0; n < 8; ++n) {
      bf16x8 bfr = *(const bf16x8*)&kpl[16 * n + l16][c0];
      acc[0][n] = mfma16(a0, bfr, acc[0][n]);
      acc[1][n] = mfma16(a1, bfr, acc[1][n]);
    }
  }

  float part[8];
#pragma unroll
  for (int n = 0; n < 8; ++n) {
    float s = 0.f;
#pragma unroll
    for (int r = 0; r < 4; ++r)
      s += __builtin_amdgcn_exp2f(acc[0][n][r]) + __builtin_amdgcn_exp2f(acc[1][n][r]);
    s += __shfl_xor(s, 16);
    s += __shfl_xor(s, 32);
    part[n] = s;
  }
  if (l < 16) {
#pragma unroll
    for (int n = 0; n < 8; ++n) cs[w][16 * n + l] = part[n];
  }
  __syncthreads();
  const int t = threadIdx.x;
  if (t < 128) {
    float s = cs[0][t] + cs[1][t] + cs[2][t] + cs[3][t];
    atomicAdd(&colsum[(size_t)b * 4096 + k0 + t], s);
  }
}

template <int NS>
__launch_bounds__(512)
__global__ void pass2_basic_kernel(const unsigned short* __restrict__ qp,
                                   const unsigned short* __restrict__ kpT,
                                   const unsigned short* __restrict__ vpN,
                                   const float* __restrict__ rcol,
                                   float* __restrict__ corr,
                                   float* __restrict__ ssP) {
  const int q0 = blockIdx.x * 64;
  const int s = blockIdx.y;
  const int b = blockIdx.z;
  const int kc0 = s * (32 / NS);
  const int w = threadIdx.x >> 6, l = threadIdx.x & 63;
  const int l16 = l & 15, lg = l >> 4;
  const int mw = w & 1, nw = w >> 1;
  const unsigned short* qb = qp + (size_t)b * 4096 * 192;
  const unsigned short* kb = kpT + (size_t)b * 4096 * 192;
  const unsigned short* vb = vpN + (size_t)b * 192 * 4096;
  const float* rc = rcol + (size_t)b * 4096;
  float* corb = corr + (size_t)b * 4096 * 4096;
  float* ssb = ssP + (size_t)(s * 4 + b) * 192 * 4096;

  __shared__ __align__(16) float cor[64][132];

  bf16x8 af[2][6];
#pragma unroll
  for (int tm = 0; tm < 2; ++tm)
#pragma unroll
    for (int ks = 0; ks < 6; ++ks)
      af[tm][ks] = *(const bf16x8*)(qb + (size_t)(q0 + 16 * (2 * mw + tm) + l16) * 192 + ks * 32 + lg * 8);

  f32x4 ssa[2][3];
#pragma unroll
  for (int tm = 0; tm < 2; ++tm)
#pragma unroll
    for (int j = 0; j < 3; ++j) ssa[tm][j] = f32x4{0, 0, 0, 0};

  for (int kc = kc0; kc < kc0 + 32 / NS; ++kc) {
    const int k0 = kc * 128;
    f32x4 sa[2][2];
#pragma unroll
    for (int tm = 0; tm < 2; ++tm)
#pragma unroll
      for (int tn = 0; tn < 2; ++tn) sa[tm][tn] = f32x4{0, 0, 0, 0};

    for (int ks = 0; ks < 6; ++ks) {
      const int c0 = ks * 32 + lg * 8;
#pragma unroll
      for (int tn = 0; tn < 2; ++tn) {
        const int kcol = k0 + 16 * (2 * nw + tn) + l16;
        bf16x8 bfr = *(const bf16x8*)(kb + (size_t)kcol * 192 + c0);
        sa[0][tn] = mfma16(af[0][ks], bfr, sa[0][tn]);
        sa[1][tn] = mfma16(af[1][ks], bfr, sa[1][tn]);
      }
    }
    float rcv[2];
#pragma unroll
    for (int tn = 0; tn < 2; ++tn) rcv[tn] = rc[k0 + 16 * (2 * nw + tn) + l16];
#pragma unroll
    for (int tm = 0; tm < 2; ++tm)
#pragma unroll
      for (int tn = 0; tn < 2; ++tn)
#pragma unroll
        for (int r = 0; r < 4; ++r)
          sa[tm][tn][r] = __builtin_amdgcn_exp2f(sa[tm][tn][r]) * rcv[tn];

    __syncthreads();
#pragma unroll
    for (int tm = 0; tm < 2; ++tm)
#pragma unroll
      for (int tn = 0; tn < 2; ++tn) {
        const int col = 16 * (2 * nw + tn) + l16;
#pragma unroll
        for (int r = 0; r < 4; ++r)
          cor[16 * (2 * mw + tm) + lg * 4 + r][col] = sa[tm][tn][r];
      }
    __syncthreads();

    {
      const int t = threadIdx.x;
#pragma unroll
      for (int it = 0; it < 4; ++it) {
        int idx = t + it * 512;
        int row = idx >> 5, seg = idx & 31;
        f32x4 v4 = *(const f32x4*)&cor[row][seg * 4];
        __builtin_nontemporal_store(v4, (f32x4*)(corb + (size_t)(q0 + row) * 4096 + k0 + seg * 4));
      }
    }

#pragma unroll
    for (int ks2 = 0; ks2 < 4; ++ks2) {
      const int cc = ks2 * 32 + lg * 8;
      bf16x8 pa[2];
#pragma unroll
      for (int tm = 0; tm < 2; ++tm) {
        f32x4 p0 = *(const f32x4*)&cor[16 * (2 * mw + tm) + l16][cc];
        f32x4 p1 = *(const f32x4*)&cor[16 * (2 * mw + tm) + l16][cc + 4];
#pragma unroll
        for (int j = 0; j < 4; ++j) {
          pa[tm][j] = (short)f2bf(p0[j]);
          pa[tm][j + 4] = (short)f2bf(p1[j]);
        }
      }
#pragma unroll
      for (int j = 0; j < 3; ++j) {
        const int ccol = 16 * (nw + 4 * j) + l16;
        bf16x8 bfr = *(const bf16x8*)(vb + (size_t)ccol * 4096 + k0 + cc);
        ssa[0][j] = mfma16(pa[0], bfr, ssa[0][j]);
        ssa[1][j] = mfma16(pa[1], bfr, ssa[1][j]);
      }
    }
  }

#pragma unroll
  for (int tm = 0; tm < 2; ++tm)
#pragma unroll
    for (int j = 0; j < 3; ++j) {
      const int ccol = 16 * (nw + 4 * j) + l16;
#pragma unroll
      for (int r = 0; r < 4; ++r) {
        const int qrow = q0 + 16 * (2 * mw + tm) + lg * 4 + r;
        ssb[(size_t)ccol * 4096 + qrow] = ssa[tm][j][r];
      }
    }
}

// ---------------- launcher ----------------
extern "C" void kernel_launch(void* const* d_in, const int* in_sizes, int n_in,
                              void* d_out, int out_size, void* d_ws, size_t ws_size,
                              hipStream_t stream) {
  (void)in_sizes; (void)n_in; (void)out_size;
  const float* lr = (const float*)d_in[0];
  const float* refine = (const float*)d_in[1];

  char* ws = (char*)d_ws;
  unsigned short* w4 = (unsigned short*)(ws + 0);                       // [0, 294912)
  float* bias4 = (float*)(ws + 294912);                                // [294912, 297984)
  unsigned short* qp = (unsigned short*)(ws + 297984);                 // 6291456 B
  unsigned short* kp = (unsigned short*)(ws + 297984 + 6291456);       // 6291456 B
  unsigned short* vp = (unsigned short*)(ws + 297984 + 2 * 6291456);   // 6291456 B -> ends 19172352
  float* colsum = (float*)(ws + 19172352);                             // 65536 B -> ends 19237888
  unsigned short* vps = (unsigned short*)(ws + 19237888);              // 6291456 B -> ends 25529344
  float* ssP = (float*)(ws + 25529344);                                // 4 slabs x 12582912 -> ends 75860992
  unsigned short* Ebuf = (unsigned short*)(ws + 75860992);             // 134217728 B -> ends 210078720
  const size_t NEW_NEED = 210078720;

  float* out0 = (float*)d_out;
  float* corr = out0 + 3145728;  // [4][4096][4096] f32

  const float alpha = (float)(1.4426950408889634 / sqrt(192.0));  // log2(e)/sqrt(C)

  PrepArgs pa;
  for (int p = 0; p < 4; ++p) {
    pa.W[p] = (const float*)d_in[2 + 5 * p];
    pa.g[p] = (const float*)d_in[3 + 5 * p];
    pa.bb[p] = (const float*)d_in[4 + 5 * p];
    pa.mm[p] = (const float*)d_in[5 + 5 * p];
    pa.vv[p] = (const float*)d_in[6 + 5 * p];
  }
  prep_all_kernel<<<dim3(144, 4), dim3(256), 0, stream>>>(pa, w4, bias4, alpha);
  hipMemsetAsync(colsum, 0, 65536, stream);

  proj_kernel<1><<<dim3(3, 64, 4), dim3(256), 0, stream>>>(refine, w4, bias4, qp);
  proj_kernel<1><<<dim3(3, 64, 4), dim3(256), 0, stream>>>(lr, w4 + 36864, bias4 + 192, kp);
  proj_kernel<0><<<dim3(3, 64, 4), dim3(256), 0, stream>>>(lr, w4 + 2 * 36864, bias4 + 2 * 192, vp);

  if (ws_size >= NEW_NEED) {
    // ---- E-materialization path ----
    pass1_e_kernel<<<dim3(32, 32, 4), dim3(256), 0, stream>>>(qp, kp, Ebuf, colsum);
    vscale_kernel<<<dim3(1536), dim3(256), 0, stream>>>(vp, colsum, vps);
    pv_kernel<<<dim3(32, 4, 4), dim3(512), 0, stream>>>(Ebuf, vps, ssP);
    proj_sum_kernel<4><<<dim3(3, 64, 4), dim3(256), 0, stream>>>(ssP, w4 + 3 * 36864, bias4 + 3 * 192, out0);
    corr_kernel<<<dim3(2048), dim3(256), 0, stream>>>(Ebuf, colsum, corr);
  } else {
    // ---- fallback: round-6 proven path (NS=2) ----
    pass1_basic_kernel<<<dim3(32, 32, 4), dim3(256), 0, stream>>>(qp, kp, colsum);
    invert_kernel<<<dim3(64), dim3(256), 0, stream>>>(colsum, 16384);
    pass2_basic_kernel<2><<<dim3(64, 2, 4), dim3(512), 0, stream>>>(qp, kp, vp, colsum, corr, ssP);
    proj_sum_kernel<2><<<dim3(3, 64, 4), dim3(256), 0, stream>>>(ssP, w4 + 3 * 36864, bias4 + 3 * 192, out0);
  }
}